// Round 1
// baseline (91.487 us; speedup 1.0000x reference)
//
#include <hip/hip_runtime.h>

// Problem constants (from reference): B=16, C=200, K=5, HW=64
constexpr int B_   = 16;
constexpr int C_   = 200;
constexpr int K_   = 5;
constexpr int HW_  = 64;
constexpr int PLANE = HW_ * HW_;            // 4096 elements per (b,c) plane
constexpr int VEC   = 4;                    // float4 per thread
constexpr int PG_PER_IMG = PLANE / VEC;     // 1024 position-groups per image
constexpr int NPG  = B_ * PG_PER_IMG;       // 16384 position-groups total
constexpr int NCHUNK = 8;                   // channel chunks
constexpr int CH   = C_ / NCHUNK;           // 25 channels per chunk
constexpr int THREADS = 256;
constexpr int BLK_PER_CHUNK = NPG / THREADS; // 64
constexpr int GRID = BLK_PER_CHUNK * NCHUNK; // 512 blocks

__global__ __launch_bounds__(THREADS) void neigh_conv_kernel(
    const float* __restrict__ x,
    const float* __restrict__ W,
    const float* __restrict__ bias,
    float* __restrict__ out)
{
    __shared__ float sW[C_ * K_];   // 4000 B
    __shared__ float sB[C_];        // 800 B
    for (int i = threadIdx.x; i < C_ * K_; i += THREADS) sW[i] = W[i];
    for (int i = threadIdx.x; i < C_;      i += THREADS) sB[i] = bias[i];
    __syncthreads();

    // chunk derived from blockIdx only -> SGPR-uniform channel loop bounds
    const int chunk = blockIdx.x / BLK_PER_CHUNK;            // 0..7
    const int pg    = (blockIdx.x % BLK_PER_CHUNK) * THREADS + threadIdx.x;
    const int b     = pg / PG_PER_IMG;
    const int pos   = (pg % PG_PER_IMG) * VEC;

    const float* xb = x   + (size_t)b * C_ * PLANE + pos;
    float*       ob = out + (size_t)b * C_ * PLANE + pos;

    const int c0 = chunk * CH;
    const int c1 = c0 + CH;

    // initial window: channels s .. s+4, s = clamp(c0-2, 0, C-K)
    int s = min(max(c0 - 2, 0), C_ - K_);
    float4 w0 = *(const float4*)(xb + (size_t)(s + 0) * PLANE);
    float4 w1 = *(const float4*)(xb + (size_t)(s + 1) * PLANE);
    float4 w2 = *(const float4*)(xb + (size_t)(s + 2) * PLANE);
    float4 w3 = *(const float4*)(xb + (size_t)(s + 3) * PLANE);
    float4 w4 = *(const float4*)(xb + (size_t)(s + 4) * PLANE);

    #pragma unroll 5
    for (int c = c0; c < c1; ++c) {
        // self channel c lives at window slot off = c - s (0..4); off==2 except near edges
        const int off = c - s;
        float4 self = (off == 2) ? w2
                    : (off == 1) ? w1
                    : (off == 0) ? w0
                    : (off == 3) ? w3
                    : w4;

        const float k0 = sW[c * K_ + 0];
        const float k1 = sW[c * K_ + 1];
        const float k2 = sW[c * K_ + 2];
        const float k3 = sW[c * K_ + 3];
        const float k4 = sW[c * K_ + 4];
        const float bb = sB[c];

        float4 o;
        o.x = self.x + bb + w0.x * k0 + w1.x * k1 + w2.x * k2 + w3.x * k3 + w4.x * k4;
        o.y = self.y + bb + w0.y * k0 + w1.y * k1 + w2.y * k2 + w3.y * k3 + w4.y * k4;
        o.z = self.z + bb + w0.z * k0 + w1.z * k1 + w2.z * k2 + w3.z * k3 + w4.z * k4;
        o.w = self.w + bb + w0.w * k0 + w1.w * k1 + w2.w * k2 + w3.w * k3 + w4.w * k4;
        *(float4*)(ob + (size_t)c * PLANE) = o;

        // advance window for channel c+1: s_next = clamp(c-1, 0, C-K)
        const int sn = min(max(c - 1, 0), C_ - K_);
        // unconditional load: when sn==s this re-loads x[s+4] which equals w4 (value-identical),
        // keeping the load address independent of the window registers for pipelining
        float4 nx = *(const float4*)(xb + (size_t)(sn + 4) * PLANE);
        if (sn != s) { w0 = w1; w1 = w2; w2 = w3; w3 = w4; }
        w4 = nx;
        s  = sn;
    }
}

extern "C" void kernel_launch(void* const* d_in, const int* in_sizes, int n_in,
                              void* d_out, int out_size, void* d_ws, size_t ws_size,
                              hipStream_t stream) {
    const float* x    = (const float*)d_in[0];
    const float* W    = (const float*)d_in[1];
    const float* bias = (const float*)d_in[2];
    float* out        = (float*)d_out;

    neigh_conv_kernel<<<GRID, THREADS, 0, stream>>>(x, W, bias, out);
}

// Round 2
// 21.792 us; speedup vs baseline: 4.1982x; 4.1982x over previous
//
#include <hip/hip_runtime.h>

// Problem constants (from reference): B=16, C=200, K=5, HW=64
constexpr int B_    = 16;
constexpr int C_    = 200;
constexpr int K_    = 5;
constexpr int HW_   = 64;
constexpr int PLANE = HW_ * HW_;             // 4096 elements per (b,c) plane
constexpr int VEC   = 4;                     // float4 per thread
constexpr int PG_PER_IMG = PLANE / VEC;      // 1024 position-groups per image
constexpr int NPG   = B_ * PG_PER_IMG;       // 16384 position-groups total
constexpr int NCHUNK = 25;                   // channel chunks
constexpr int CH    = C_ / NCHUNK;           // 8 channels per chunk
constexpr int NLD   = CH + 4;                // 12 channels loaded per chunk (halo)
constexpr int THREADS = 256;
constexpr int BLKX  = NPG / THREADS;         // 64 blocks in position dim

// MODE: 0 = first chunk (c0==0), 1 = interior, 2 = last chunk (c0==C-CH)
template<int MODE>
__device__ __forceinline__ void body(int c0,
                                     const float* __restrict__ xb,
                                     const float* __restrict__ W,
                                     const float* __restrict__ bias,
                                     float* __restrict__ ob)
{
    // contiguous strip of NLD channels covering every clamped window of this chunk
    const int cs = (MODE == 0) ? 0 : (MODE == 2 ? (C_ - NLD) : (c0 - 2));

    // issue all strip loads up-front: NLD independent 16B loads in flight
    float4 r[NLD];
    #pragma unroll
    for (int i = 0; i < NLD; ++i)
        r[i] = *(const float4*)(xb + (size_t)(cs + i) * PLANE);

    #pragma unroll
    for (int i = 0; i < CH; ++i) {
        const int c = c0 + i;
        // window start offset into r[] — compile-time constant after unroll
        int off;
        if (MODE == 0)      off = (i < 2) ? 0 : (i - 2);        // s = max(c-2,0)
        else if (MODE == 2) off = (i + 2 > NLD - K_) ? (NLD - K_) : (i + 2); // s = min(c-2, C-K)
        else                off = i;                             // s = c-2
        // self channel index into r[]
        int si;
        if (MODE == 0)      si = i;
        else if (MODE == 2) si = i + 4;
        else                si = i + 2;

        // uniform (blockIdx-derived) addresses -> scalar loads, K$-cached
        const float k0 = W[c * K_ + 0];
        const float k1 = W[c * K_ + 1];
        const float k2 = W[c * K_ + 2];
        const float k3 = W[c * K_ + 3];
        const float k4 = W[c * K_ + 4];
        const float bb = bias[c];

        const float4 self = r[si];
        float4 o;
        o.x = self.x + bb + r[off].x * k0 + r[off+1].x * k1 + r[off+2].x * k2 + r[off+3].x * k3 + r[off+4].x * k4;
        o.y = self.y + bb + r[off].y * k0 + r[off+1].y * k1 + r[off+2].y * k2 + r[off+3].y * k3 + r[off+4].y * k4;
        o.z = self.z + bb + r[off].z * k0 + r[off+1].z * k1 + r[off+2].z * k2 + r[off+3].z * k3 + r[off+4].z * k4;
        o.w = self.w + bb + r[off].w * k0 + r[off+1].w * k1 + r[off+2].w * k2 + r[off+3].w * k3 + r[off+4].w * k4;
        *(float4*)(ob + (size_t)c * PLANE) = o;
    }
}

__global__ __launch_bounds__(THREADS) void neigh_conv_kernel(
    const float* __restrict__ x,
    const float* __restrict__ W,
    const float* __restrict__ bias,
    float* __restrict__ out)
{
    const int chunk = blockIdx.y;                 // 0..NCHUNK-1, wave-uniform
    const int c0    = chunk * CH;
    const int pg    = blockIdx.x * THREADS + threadIdx.x;  // 0..NPG-1
    const int b     = pg / PG_PER_IMG;
    const int pos   = (pg % PG_PER_IMG) * VEC;

    const float* xb = x   + (size_t)b * C_ * PLANE + pos;
    float*       ob = out + (size_t)b * C_ * PLANE + pos;

    if (chunk == 0)                body<0>(c0, xb, W, bias, ob);
    else if (chunk == NCHUNK - 1)  body<2>(c0, xb, W, bias, ob);
    else                           body<1>(c0, xb, W, bias, ob);
}

extern "C" void kernel_launch(void* const* d_in, const int* in_sizes, int n_in,
                              void* d_out, int out_size, void* d_ws, size_t ws_size,
                              hipStream_t stream) {
    const float* x    = (const float*)d_in[0];
    const float* W    = (const float*)d_in[1];
    const float* bias = (const float*)d_in[2];
    float* out        = (float*)d_out;

    dim3 grid(BLKX, NCHUNK);
    neigh_conv_kernel<<<grid, THREADS, 0, stream>>>(x, W, bias, out);
}

// Round 4
// 21.428 us; speedup vs baseline: 4.2696x; 1.0170x over previous
//
#include <hip/hip_runtime.h>

// Problem constants (from reference): B=16, C=200, K=5, HW=64
constexpr int B_    = 16;
constexpr int C_    = 200;
constexpr int K_    = 5;
constexpr int HW_   = 64;
constexpr int PLANE = HW_ * HW_;             // 4096 elements per (b,c) plane
constexpr int VEC   = 4;                     // float4 per thread
constexpr int PG_PER_IMG = PLANE / VEC;      // 1024 position-groups per image
constexpr int NPG   = B_ * PG_PER_IMG;       // 16384 position-groups total
constexpr int NCHUNK = 20;                   // channel chunks
constexpr int CH    = C_ / NCHUNK;           // 10 channels per chunk
constexpr int THREADS = 256;
constexpr int BLKX  = NPG / THREADS;         // 64 blocks in position dim

typedef float v4f __attribute__((ext_vector_type(4)));  // native vector for nontemporal builtin

// MODE: 0 = first chunk (c0==0), 1 = interior, 2 = last chunk (c0==C-CH)
// NLD: strip length (12 for edge chunks, 14 for interior)
template<int MODE, int NLD>
__device__ __forceinline__ void body(int c0,
                                     const float* __restrict__ xb,
                                     const float* __restrict__ W,
                                     const float* __restrict__ bias,
                                     float* __restrict__ ob)
{
    // contiguous strip of NLD channels covering every clamped window of this chunk
    const int cs = (MODE == 0) ? 0 : (MODE == 2 ? (C_ - NLD) : (c0 - 2));

    // issue all strip loads up-front: NLD independent 16B loads in flight
    v4f r[NLD];
    #pragma unroll
    for (int i = 0; i < NLD; ++i)
        r[i] = *(const v4f*)(xb + (size_t)(cs + i) * PLANE);

    #pragma unroll
    for (int i = 0; i < CH; ++i) {
        const int c = c0 + i;
        // window start offset into r[] — compile-time constant after unroll
        int off;
        if (MODE == 0)      off = (i < 2) ? 0 : (i - 2);          // s = max(c-2,0)
        else if (MODE == 2) off = (i < 7) ? (i) : 7;              // s = min(c-2, C-K); cs=C-12
        else                off = i;                              // s = c-2
        // self channel index into r[]
        int si;
        if (MODE == 0)      si = i;
        else                si = i + 2;                           // interior & last: c-cs = i+2

        // uniform (blockIdx-derived) addresses -> scalar loads, K$-cached
        const float k0 = W[c * K_ + 0];
        const float k1 = W[c * K_ + 1];
        const float k2 = W[c * K_ + 2];
        const float k3 = W[c * K_ + 3];
        const float k4 = W[c * K_ + 4];
        const float bb = bias[c];

        const v4f self = r[si];
        v4f o = self + bb + r[off] * k0 + r[off+1] * k1 + r[off+2] * k2 + r[off+3] * k3 + r[off+4] * k4;
        // non-temporal: out is write-once, keep it from displacing x in L2/L3
        __builtin_nontemporal_store(o, (v4f*)(ob + (size_t)c * PLANE));
    }
}

__global__ __launch_bounds__(THREADS) void neigh_conv_kernel(
    const float* __restrict__ x,
    const float* __restrict__ W,
    const float* __restrict__ bias,
    float* __restrict__ out)
{
    const int chunk = blockIdx.y;                 // 0..NCHUNK-1, wave-uniform
    const int c0    = chunk * CH;
    const int pg    = blockIdx.x * THREADS + threadIdx.x;  // 0..NPG-1
    const int b     = pg / PG_PER_IMG;
    const int pos   = (pg % PG_PER_IMG) * VEC;

    const float* xb = x   + (size_t)b * C_ * PLANE + pos;
    float*       ob = out + (size_t)b * C_ * PLANE + pos;

    if (chunk == 0)                body<0, CH + 2>(c0, xb, W, bias, ob);
    else if (chunk == NCHUNK - 1)  body<2, CH + 2>(c0, xb, W, bias, ob);
    else                           body<1, CH + 4>(c0, xb, W, bias, ob);
}

extern "C" void kernel_launch(void* const* d_in, const int* in_sizes, int n_in,
                              void* d_out, int out_size, void* d_ws, size_t ws_size,
                              hipStream_t stream) {
    const float* x    = (const float*)d_in[0];
    const float* W    = (const float*)d_in[1];
    const float* bias = (const float*)d_in[2];
    float* out        = (float*)d_out;

    dim3 grid(BLKX, NCHUNK);
    neigh_conv_kernel<<<grid, THREADS, 0, stream>>>(x, W, bias, out);
}